// Round 2
// baseline (357.911 us; speedup 1.0000x reference)
//
#include <hip/hip_runtime.h>

// y[e, o] = sum_i weight[widx[e]][o][i] * values[iidx[e]][i]
// E = 1e6, N_W = 1024, D_IN = D_OUT = 16, fp32.
//
// R1 was latency/transaction-bound: E x 1KB weight gather = 16e6 random L2
// lines (Little's law: 150 outstanding / ~700cy = 0.21 lines/cy/CU -> 131us,
// matched measurement). Fix: counting-sort connections by weight_idx, then
// one block per bucket keeps its weight matrix entirely in registers.
//
// Pipeline (all on stream, graph-capture safe):
//   1. hipMemsetAsync hist (4KB)
//   2. hist_kernel: LDS histogram -> global
//   3. scan_kernel: 1024-wide exclusive scan -> offsets, cursors
//   4. scatter_kernel: pos = atomicAdd(cursor[wi]); perm_e/perm_ii[pos]
//   5. bucket_mv: block = (bucket, segment); W in 64 VGPRs/lane;
//      only random traffic = x gather (1 line/conn) + out write (1 line/conn)

#define D 16
#define NWMAX 1024

// ---------------- fallback naive kernel (R1) ----------------
__global__ __launch_bounds__(256) void linear_gather_mv(
    const float* __restrict__ values, const float* __restrict__ weight,
    const int* __restrict__ input_idx, const int* __restrict__ weight_idx,
    float* __restrict__ out, int E)
{
    int tid = blockIdx.x * blockDim.x + threadIdx.x;
    int e = tid >> 2;
    int j = tid & 3;
    if (e >= E) return;
    int ii = input_idx[e];
    int wi = weight_idx[e];
    const float4* xp = (const float4*)(values + (long long)ii * D);
    float4 x0 = xp[0], x1 = xp[1], x2 = xp[2], x3 = xp[3];
    const float4* wp = (const float4*)(weight + (long long)wi * (D * D) + j * (4 * D));
    float4 acc;
    float* accp = (float*)&acc;
    #pragma unroll
    for (int r = 0; r < 4; ++r) {
        float4 w0 = wp[r * 4 + 0], w1 = wp[r * 4 + 1], w2 = wp[r * 4 + 2], w3 = wp[r * 4 + 3];
        accp[r] = w0.x * x0.x + w0.y * x0.y + w0.z * x0.z + w0.w * x0.w
                + w1.x * x1.x + w1.y * x1.y + w1.z * x1.z + w1.w * x1.w
                + w2.x * x2.x + w2.y * x2.y + w2.z * x2.z + w2.w * x2.w
                + w3.x * x3.x + w3.y * x3.y + w3.z * x3.z + w3.w * x3.w;
    }
    ((float4*)out)[(long long)e * 4 + j] = acc;
}

// ---------------- phase 1: histogram ----------------
__global__ __launch_bounds__(256) void hist_kernel(
    const int* __restrict__ widx, int E, int* __restrict__ hist, int NW)
{
    __shared__ int lh[NWMAX];
    for (int i = threadIdx.x; i < NW; i += blockDim.x) lh[i] = 0;
    __syncthreads();
    int stride = gridDim.x * blockDim.x;
    for (int e = blockIdx.x * blockDim.x + threadIdx.x; e < E; e += stride)
        atomicAdd(&lh[widx[e]], 1);
    __syncthreads();
    for (int i = threadIdx.x; i < NW; i += blockDim.x) {
        int v = lh[i];
        if (v) atomicAdd(&hist[i], v);
    }
}

// ---------------- phase 2: exclusive scan over NW<=1024 bins ----------------
__global__ __launch_bounds__(1024) void scan_kernel(
    const int* __restrict__ hist, int* __restrict__ offsets,
    int* __restrict__ cursors, int NW)
{
    __shared__ int buf[2 * NWMAX];
    int t = threadIdx.x;
    int v = (t < NW) ? hist[t] : 0;
    buf[t] = v;
    __syncthreads();
    int pin = 0;
    for (int off = 1; off < NWMAX; off <<= 1) {
        int x = buf[pin * NWMAX + t];
        if (t >= off) x += buf[pin * NWMAX + t - off];
        buf[(1 - pin) * NWMAX + t] = x;
        pin = 1 - pin;
        __syncthreads();
    }
    int incl = buf[pin * NWMAX + t];
    if (t < NW) {
        offsets[t + 1] = incl;       // exclusive offsets: offsets[i] .. offsets[i+1]
        cursors[t] = incl - v;
        if (t == 0) offsets[0] = 0;
    }
}

// ---------------- phase 3: scatter into buckets ----------------
__global__ __launch_bounds__(256) void scatter_kernel(
    const int* __restrict__ widx, const int* __restrict__ iidx, int E,
    int* __restrict__ cursors, int* __restrict__ perm_e, int* __restrict__ perm_ii)
{
    int stride = gridDim.x * blockDim.x;
    for (int e = blockIdx.x * blockDim.x + threadIdx.x; e < E; e += stride) {
        int wi = widx[e];
        int pos = atomicAdd(&cursors[wi], 1);
        perm_e[pos] = e;
        perm_ii[pos] = iidx[e];
    }
}

// ---------------- phase 4: per-bucket matvec, W in registers ----------------
__global__ __launch_bounds__(256) void bucket_mv(
    const float* __restrict__ values, const float* __restrict__ weight,
    const int* __restrict__ offsets, const int* __restrict__ perm_e,
    const int* __restrict__ perm_ii, float* __restrict__ out)
{
    int b = blockIdx.x;                  // weight bucket
    int lo = offsets[b], hi = offsets[b + 1];
    int cnt = hi - lo;
    if (cnt == 0) return;
    int per = (cnt + gridDim.y - 1) / gridDim.y;
    int s0 = lo + blockIdx.y * per;
    int s1 = min(hi, s0 + per);
    if (s0 >= s1) return;

    int j = threadIdx.x & 3;             // 4-row slab of the output
    int g = threadIdx.x >> 2;            // 64 connection-groups per block

    // rows [4j, 4j+4) of W[b], kept in 64 VGPRs for the whole bucket
    const float4* wp = (const float4*)(weight + (long long)b * (D * D) + j * (4 * D));
    float4 w00 = wp[0],  w01 = wp[1],  w02 = wp[2],  w03 = wp[3];
    float4 w10 = wp[4],  w11 = wp[5],  w12 = wp[6],  w13 = wp[7];
    float4 w20 = wp[8],  w21 = wp[9],  w22 = wp[10], w23 = wp[11];
    float4 w30 = wp[12], w31 = wp[13], w32 = wp[14], w33 = wp[15];

    for (int k = s0 + g; k < s1; k += 64) {
        int e  = perm_e[k];
        int ii = perm_ii[k];
        const float4* xp = (const float4*)(values + (long long)ii * D);
        float4 x0 = xp[0], x1 = xp[1], x2 = xp[2], x3 = xp[3];

        float4 acc;
        acc.x = w00.x * x0.x + w00.y * x0.y + w00.z * x0.z + w00.w * x0.w
              + w01.x * x1.x + w01.y * x1.y + w01.z * x1.z + w01.w * x1.w
              + w02.x * x2.x + w02.y * x2.y + w02.z * x2.z + w02.w * x2.w
              + w03.x * x3.x + w03.y * x3.y + w03.z * x3.z + w03.w * x3.w;
        acc.y = w10.x * x0.x + w10.y * x0.y + w10.z * x0.z + w10.w * x0.w
              + w11.x * x1.x + w11.y * x1.y + w11.z * x1.z + w11.w * x1.w
              + w12.x * x2.x + w12.y * x2.y + w12.z * x2.z + w12.w * x2.w
              + w13.x * x3.x + w13.y * x3.y + w13.z * x3.z + w13.w * x3.w;
        acc.z = w20.x * x0.x + w20.y * x0.y + w20.z * x0.z + w20.w * x0.w
              + w21.x * x1.x + w21.y * x1.y + w21.z * x1.z + w21.w * x1.w
              + w22.x * x2.x + w22.y * x2.y + w22.z * x2.z + w22.w * x2.w
              + w23.x * x3.x + w23.y * x3.y + w23.z * x3.z + w23.w * x3.w;
        acc.w = w30.x * x0.x + w30.y * x0.y + w30.z * x0.z + w30.w * x0.w
              + w31.x * x1.x + w31.y * x1.y + w31.z * x1.z + w31.w * x1.w
              + w32.x * x2.x + w32.y * x2.y + w32.z * x2.z + w32.w * x2.w
              + w33.x * x3.x + w33.y * x3.y + w33.z * x3.z + w33.w * x3.w;

        ((float4*)out)[(long long)e * 4 + j] = acc;
    }
}

extern "C" void kernel_launch(void* const* d_in, const int* in_sizes, int n_in,
                              void* d_out, int out_size, void* d_ws, size_t ws_size,
                              hipStream_t stream) {
    const float* values     = (const float*)d_in[0];
    const float* weight     = (const float*)d_in[1];
    const int*   input_idx  = (const int*)d_in[2];
    const int*   weight_idx = (const int*)d_in[3];
    float*       out        = (float*)d_out;

    int E  = in_sizes[2];
    int NW = in_sizes[1] / (D * D);

    // workspace layout (ints)
    int* ws      = (int*)d_ws;
    int* hist    = ws;                 // [NWMAX]
    int* offsets = ws + NWMAX;         // [NWMAX + 1]
    int* cursors = ws + 2 * NWMAX + 4; // [NWMAX]
    int* perm_e  = ws + 4 * NWMAX;     // [E]
    // perm_ii follows perm_e
    size_t need = ((size_t)4 * NWMAX + 2 * (size_t)E) * sizeof(int);

    if (NW > NWMAX || ws_size < need) {
        // fallback: naive (R1) kernel
        int total = E * 4;
        int block = 256;
        int grid = (total + block - 1) / block;
        hipLaunchKernelGGL(linear_gather_mv, dim3(grid), dim3(block), 0, stream,
                           values, weight, input_idx, weight_idx, out, E);
        return;
    }
    int* perm_ii = perm_e + E;

    hipMemsetAsync(hist, 0, NWMAX * sizeof(int), stream);

    hipLaunchKernelGGL(hist_kernel, dim3(256), dim3(256), 0, stream,
                       weight_idx, E, hist, NW);
    hipLaunchKernelGGL(scan_kernel, dim3(1), dim3(1024), 0, stream,
                       hist, offsets, cursors, NW);
    hipLaunchKernelGGL(scatter_kernel, dim3(1024), dim3(256), 0, stream,
                       weight_idx, input_idx, E, cursors, perm_e, perm_ii);
    hipLaunchKernelGGL(bucket_mv, dim3(NW, 2), dim3(256), 0, stream,
                       values, weight, offsets, perm_e, perm_ii, out);
}

// Round 3
// 196.949 us; speedup vs baseline: 1.8173x; 1.8173x over previous
//
#include <hip/hip_runtime.h>

// y[e, o] = sum_i weight[widx[e]][o][i] * values[iidx[e]][i]
// E = 1e6, N_W = 1024, D_IN = D_OUT = 16, fp32.
//
// R1: latency-bound weight gather (16e6 random L2 lines) -> 137 us.
// R2: bucket sort fixed the gather but global atomicAdd on 1024 cursors
//     serialized (977 collisions/addr) -> scatter 203 us.
// R3: deterministic two-level counting sort, ZERO global atomics:
//     hist_blocks (per-block private rows) -> scan_per_bin (in-place) ->
//     scan_bins -> scatter_det (LDS cursors) -> bucket_mv (W in VGPRs).

#define D 16
#define NWMAX 1024
#define NB 256      // sort blocks == chunks
#define BT 256      // threads per block

// ---------------- fallback naive kernel (R1, 137us) ----------------
__global__ __launch_bounds__(256) void linear_gather_mv(
    const float* __restrict__ values, const float* __restrict__ weight,
    const int* __restrict__ input_idx, const int* __restrict__ weight_idx,
    float* __restrict__ out, int E)
{
    int tid = blockIdx.x * blockDim.x + threadIdx.x;
    int e = tid >> 2;
    int j = tid & 3;
    if (e >= E) return;
    int ii = input_idx[e];
    int wi = weight_idx[e];
    const float4* xp = (const float4*)(values + (long long)ii * D);
    float4 x0 = xp[0], x1 = xp[1], x2 = xp[2], x3 = xp[3];
    const float4* wp = (const float4*)(weight + (long long)wi * (D * D) + j * (4 * D));
    float4 acc;
    float* accp = (float*)&acc;
    #pragma unroll
    for (int r = 0; r < 4; ++r) {
        float4 w0 = wp[r * 4 + 0], w1 = wp[r * 4 + 1], w2 = wp[r * 4 + 2], w3 = wp[r * 4 + 3];
        accp[r] = w0.x * x0.x + w0.y * x0.y + w0.z * x0.z + w0.w * x0.w
                + w1.x * x1.x + w1.y * x1.y + w1.z * x1.z + w1.w * x1.w
                + w2.x * x2.x + w2.y * x2.y + w2.z * x2.z + w2.w * x2.w
                + w3.x * x3.x + w3.y * x3.y + w3.z * x3.z + w3.w * x3.w;
    }
    ((float4*)out)[(long long)e * 4 + j] = acc;
}

// ---------------- phase 1: per-block private histograms ----------------
__global__ __launch_bounds__(BT) void hist_blocks(
    const int* __restrict__ widx, int E, int chunk,
    int* __restrict__ hist2d, int NW)
{
    __shared__ int lh[NWMAX];
    for (int i = threadIdx.x; i < NW; i += BT) lh[i] = 0;
    __syncthreads();
    int s0 = blockIdx.x * chunk;
    int s1 = min(E, s0 + chunk);
    for (int e = s0 + threadIdx.x; e < s1; e += BT)
        atomicAdd(&lh[widx[e]], 1);   // LDS atomic only
    __syncthreads();
    int* row = hist2d + (long long)blockIdx.x * NW;
    for (int i = threadIdx.x; i < NW; i += BT) row[i] = lh[i];
}

// ------- phase 2a: per-bin exclusive scan across blocks (in place) -------
__global__ __launch_bounds__(NB) void scan_per_bin(
    int* __restrict__ hist2d, int* __restrict__ total, int NW)
{
    __shared__ int buf[2 * NB];
    int b = blockIdx.x;   // bin
    int t = threadIdx.x;  // sort-block index
    int v = hist2d[(long long)t * NW + b];
    buf[t] = v;
    __syncthreads();
    int pin = 0;
    for (int off = 1; off < NB; off <<= 1) {
        int x = buf[pin * NB + t];
        if (t >= off) x += buf[pin * NB + t - off];
        buf[(1 - pin) * NB + t] = x;
        pin = 1 - pin;
        __syncthreads();
    }
    int incl = buf[pin * NB + t];
    hist2d[(long long)t * NW + b] = incl - v;   // exclusive prefix for (bin, block)
    if (t == NB - 1) total[b] = incl;
}

// ---------------- phase 2b: scan over bins -> bucket offsets ----------------
__global__ __launch_bounds__(1024) void scan_bins(
    const int* __restrict__ total, int* __restrict__ offsets, int NW)
{
    __shared__ int buf[2 * NWMAX];
    int t = threadIdx.x;
    int v = (t < NW) ? total[t] : 0;
    buf[t] = v;
    __syncthreads();
    int pin = 0;
    for (int off = 1; off < NWMAX; off <<= 1) {
        int x = buf[pin * NWMAX + t];
        if (t >= off) x += buf[pin * NWMAX + t - off];
        buf[(1 - pin) * NWMAX + t] = x;
        pin = 1 - pin;
        __syncthreads();
    }
    int incl = buf[pin * NWMAX + t];
    if (t < NW) {
        offsets[t + 1] = incl;
        if (t == 0) offsets[0] = 0;
    }
}

// ---------------- phase 3: deterministic scatter, LDS cursors ----------------
__global__ __launch_bounds__(BT) void scatter_det(
    const int* __restrict__ widx, const int* __restrict__ iidx, int E, int chunk,
    const int* __restrict__ hist2d, const int* __restrict__ offsets,
    int2* __restrict__ perm, int NW)
{
    __shared__ int cur[NWMAX];
    int p = blockIdx.x;
    const int* row = hist2d + (long long)p * NW;
    for (int i = threadIdx.x; i < NW; i += BT)
        cur[i] = offsets[i] + row[i];
    __syncthreads();
    int s0 = p * chunk;
    int s1 = min(E, s0 + chunk);
    for (int e = s0 + threadIdx.x; e < s1; e += BT) {
        int wi = widx[e];
        int pos = atomicAdd(&cur[wi], 1);   // LDS atomic, ~4 collisions/bin
        perm[pos] = make_int2(e, iidx[e]);
    }
}

// ---------------- phase 4: per-bucket matvec, W in registers ----------------
#define SEG 8
__global__ __launch_bounds__(256) void bucket_mv(
    const float* __restrict__ values, const float* __restrict__ weight,
    const int* __restrict__ offsets, const int2* __restrict__ perm,
    float* __restrict__ out)
{
    int b = blockIdx.x;                  // weight bucket
    int lo = offsets[b], hi = offsets[b + 1];
    int cnt = hi - lo;
    if (cnt == 0) return;
    int per = (cnt + SEG - 1) / SEG;
    int s0 = lo + blockIdx.y * per;
    int s1 = min(hi, s0 + per);
    if (s0 >= s1) return;

    int j = threadIdx.x & 3;             // 4-row slab of the output
    int g = threadIdx.x >> 2;            // 64 connection-groups per block

    const float4* wp = (const float4*)(weight + (long long)b * (D * D) + j * (4 * D));
    float4 w00 = wp[0],  w01 = wp[1],  w02 = wp[2],  w03 = wp[3];
    float4 w10 = wp[4],  w11 = wp[5],  w12 = wp[6],  w13 = wp[7];
    float4 w20 = wp[8],  w21 = wp[9],  w22 = wp[10], w23 = wp[11];
    float4 w30 = wp[12], w31 = wp[13], w32 = wp[14], w33 = wp[15];

    for (int k = s0 + g; k < s1; k += 64) {
        int2 pe = perm[k];
        const float4* xp = (const float4*)(values + (long long)pe.y * D);
        float4 x0 = xp[0], x1 = xp[1], x2 = xp[2], x3 = xp[3];

        float4 acc;
        acc.x = w00.x * x0.x + w00.y * x0.y + w00.z * x0.z + w00.w * x0.w
              + w01.x * x1.x + w01.y * x1.y + w01.z * x1.z + w01.w * x1.w
              + w02.x * x2.x + w02.y * x2.y + w02.z * x2.z + w02.w * x2.w
              + w03.x * x3.x + w03.y * x3.y + w03.z * x3.z + w03.w * x3.w;
        acc.y = w10.x * x0.x + w10.y * x0.y + w10.z * x0.z + w10.w * x0.w
              + w11.x * x1.x + w11.y * x1.y + w11.z * x1.z + w11.w * x1.w
              + w12.x * x2.x + w12.y * x2.y + w12.z * x2.z + w12.w * x2.w
              + w13.x * x3.x + w13.y * x3.y + w13.z * x3.z + w13.w * x3.w;
        acc.z = w20.x * x0.x + w20.y * x0.y + w20.z * x0.z + w20.w * x0.w
              + w21.x * x1.x + w21.y * x1.y + w21.z * x1.z + w21.w * x1.w
              + w22.x * x2.x + w22.y * x2.y + w22.z * x2.z + w22.w * x2.w
              + w23.x * x3.x + w23.y * x3.y + w23.z * x3.z + w23.w * x3.w;
        acc.w = w30.x * x0.x + w30.y * x0.y + w30.z * x0.z + w30.w * x0.w
              + w31.x * x1.x + w31.y * x1.y + w31.z * x1.z + w31.w * x1.w
              + w32.x * x2.x + w32.y * x2.y + w32.z * x2.z + w32.w * x2.w
              + w33.x * x3.x + w33.y * x3.y + w33.z * x3.z + w33.w * x3.w;

        ((float4*)out)[(long long)pe.x * 4 + j] = acc;
    }
}

extern "C" void kernel_launch(void* const* d_in, const int* in_sizes, int n_in,
                              void* d_out, int out_size, void* d_ws, size_t ws_size,
                              hipStream_t stream) {
    const float* values     = (const float*)d_in[0];
    const float* weight     = (const float*)d_in[1];
    const int*   input_idx  = (const int*)d_in[2];
    const int*   weight_idx = (const int*)d_in[3];
    float*       out        = (float*)d_out;

    int E  = in_sizes[2];
    int NW = in_sizes[1] / (D * D);

    // workspace layout (ints): hist2d[NB*NW] | total[NW] | offsets[NW+1] | pad | perm[2*E]
    size_t n_hist = (size_t)NB * NW;
    size_t n_head = n_hist + NW + NW + 1;
    n_head = (n_head + 1) & ~(size_t)1;            // 8B-align perm
    size_t need = (n_head + 2 * (size_t)E) * sizeof(int);

    if (NW > NWMAX || ws_size < need) {
        int total_thr = E * 4;
        int grid = (total_thr + 255) / 256;
        hipLaunchKernelGGL(linear_gather_mv, dim3(grid), dim3(256), 0, stream,
                           values, weight, input_idx, weight_idx, out, E);
        return;
    }

    int* ws      = (int*)d_ws;
    int* hist2d  = ws;
    int* total   = ws + n_hist;
    int* offsets = total + NW;
    int2* perm   = (int2*)(ws + n_head);

    int chunk = (E + NB - 1) / NB;

    hipLaunchKernelGGL(hist_blocks, dim3(NB), dim3(BT), 0, stream,
                       weight_idx, E, chunk, hist2d, NW);
    hipLaunchKernelGGL(scan_per_bin, dim3(NW), dim3(NB), 0, stream,
                       hist2d, total, NW);
    hipLaunchKernelGGL(scan_bins, dim3(1), dim3(1024), 0, stream,
                       total, offsets, NW);
    hipLaunchKernelGGL(scatter_det, dim3(NB), dim3(BT), 0, stream,
                       weight_idx, input_idx, E, chunk, hist2d, offsets, perm, NW);
    hipLaunchKernelGGL(bucket_mv, dim3(NW, SEG), dim3(256), 0, stream,
                       values, weight, offsets, perm, out);
}